// Round 1
// baseline (151.047 us; speedup 1.0000x reference)
//
#include <hip/hip_runtime.h>

#define NDIR  6
#define B_    16
#define N_IN  16384
#define N_OUT 8192
#define IDIM  128
#define ODIM  128
#define TOTAL (B_ * N_OUT)   // 131072 nodes
#define BM    64
#define BK    64

// d_ws layout (as ints): [0..7]=cnt, [8..14]=offsets (offsets[6]=total),
// [16..23]=cursors, ids at int offset 64 (TOTAL ints -> ~512KB + 256B total)
#define WS_CNT 0
#define WS_OFF 8
#define WS_CUR 16
#define WS_IDS 64

__global__ void zero_kernel(int* ws) {
    int t = threadIdx.x;
    if (t < 32) ws[t] = 0;
}

__global__ void count_kernel(const int* __restrict__ vec, const int* __restrict__ dmap,
                             int* __restrict__ ws) {
    __shared__ int h[NDIR];
    int t = threadIdx.x;
    if (t < NDIR) h[t] = 0;
    __syncthreads();
    int id = blockIdx.x * 256 + t;
    if (id < TOTAL) {
        int d = dmap[vec[id]];
        atomicAdd(&h[d], 1);
    }
    __syncthreads();
    if (t < NDIR && h[t]) atomicAdd(&ws[WS_CNT + t], h[t]);
}

__global__ void prefix_kernel(int* ws) {
    if (threadIdx.x == 0) {
        int acc = 0;
        for (int i = 0; i < NDIR; ++i) {
            ws[WS_OFF + i] = acc;
            ws[WS_CUR + i] = acc;
            acc += ws[WS_CNT + i];
        }
        ws[WS_OFF + NDIR] = acc;
    }
}

__global__ void scatter_kernel(const int* __restrict__ vec, const int* __restrict__ dmap,
                               int* __restrict__ ws) {
    __shared__ int h[NDIR];
    __shared__ int base[NDIR];
    int t = threadIdx.x;
    if (t < NDIR) h[t] = 0;
    __syncthreads();
    int id = blockIdx.x * 256 + t;
    int d = 0, pos = 0;
    if (id < TOTAL) {
        d = dmap[vec[id]];
        pos = atomicAdd(&h[d], 1);
    }
    __syncthreads();
    if (t < NDIR) base[t] = h[t] ? atomicAdd(&ws[WS_CUR + t], h[t]) : 0;
    __syncthreads();
    if (id < TOTAL) ws[WS_IDS + base[d] + pos] = id;
}

// Grouped gather-GEMM: one block = 64 nodes (same direction) x 128 outputs.
// K = 256 (pair = [first-child 128 | second-child 128]), looped in 4 chunks of 64.
__global__ __launch_bounds__(256) void gemm_kernel(
    const float* __restrict__ last, const float* __restrict__ W,
    const float* __restrict__ bias, const float* __restrict__ alphap,
    const int* __restrict__ vec, const int* __restrict__ drev,
    const int* __restrict__ child_l, const int* __restrict__ child_r,
    const int* __restrict__ ws, float* __restrict__ out)
{
    int dir = blockIdx.y;
    int start = ws[WS_OFF + dir];
    int end   = ws[WS_OFF + dir + 1];
    int m0 = start + (int)blockIdx.x * BM;
    if (m0 >= end) return;
    const int* ids = ws + WS_IDS;

    __shared__ int s_row0[BM], s_row1[BM], s_oid[BM];
    __shared__ float As[BM][BK + 4];
    __shared__ float Wl[BK][ODIM + 4];

    int t = threadIdx.x;
    if (t < BM) {
        int idx = m0 + t;
        bool valid = idx < end;
        int id = ids[valid ? idx : end - 1];
        int b = id >> 13;            // N_OUT = 8192
        int n = id & (N_OUT - 1);
        int v = vec[id];
        int r = drev[v];
        int cl = child_l[n];
        int cr = child_r[n];
        int first  = r ? cr : cl;
        int second = r ? cl : cr;
        s_row0[t] = b * N_IN + first;
        s_row1[t] = b * N_IN + second;
        s_oid[t]  = valid ? id : -1;
    }
    __syncthreads();

    float acc[4][8];
    #pragma unroll
    for (int c = 0; c < 4; ++c)
        #pragma unroll
        for (int j = 0; j < 8; ++j) acc[c][j] = 0.f;

    const float* Wd = W + (size_t)dir * (2 * IDIM * ODIM);
    int ng = t >> 4;   // 0..15 -> nodes ng*4..ng*4+3
    int og = t & 15;   // 0..15 -> outputs og*8..og*8+7

    for (int kc = 0; kc < 4; ++kc) {
        int dim0 = (kc & 1) * 64;
        const int* srow = (kc < 2) ? s_row0 : s_row1;
        // stage A: 64 rows x 64 floats; 16 lanes cover one row (256B contiguous)
        {
            int rg = t >> 4, c4 = t & 15;
            #pragma unroll
            for (int j = 0; j < 4; ++j) {
                int row = rg + j * 16;
                const float* src = last + (size_t)srow[row] * IDIM + dim0 + c4 * 4;
                *(float4*)&As[row][c4 * 4] = *(const float4*)src;
            }
        }
        // stage W chunk: rows kc*64..+63, 128 floats each (512B contiguous per row)
        {
            int r8 = t >> 5, c4 = t & 31;
            #pragma unroll
            for (int j = 0; j < 8; ++j) {
                int row = r8 + j * 8;
                const float* src = Wd + (size_t)(kc * 64 + row) * ODIM + c4 * 4;
                *(float4*)&Wl[row][c4 * 4] = *(const float4*)src;
            }
        }
        __syncthreads();

        for (int k = 0; k < BK; k += 4) {
            float a[4][4];
            #pragma unroll
            for (int c = 0; c < 4; ++c)
                *(float4*)&a[c][0] = *(const float4*)&As[ng * 4 + c][k];
            #pragma unroll
            for (int kk = 0; kk < 4; ++kk) {
                float w[8];
                *(float4*)&w[0] = *(const float4*)&Wl[k + kk][og * 8];
                *(float4*)&w[4] = *(const float4*)&Wl[k + kk][og * 8 + 4];
                #pragma unroll
                for (int c = 0; c < 4; ++c) {
                    float av = a[c][kk];
                    #pragma unroll
                    for (int j = 0; j < 8; ++j) acc[c][j] += av * w[j];
                }
            }
        }
        __syncthreads();
    }

    float alpha = alphap[0];
    float bb[8];
    *(float4*)&bb[0] = *(const float4*)&bias[dir * ODIM + og * 8];
    *(float4*)&bb[4] = *(const float4*)&bias[dir * ODIM + og * 8 + 4];
    #pragma unroll
    for (int c = 0; c < 4; ++c) {
        int id = s_oid[ng * 4 + c];
        if (id < 0) continue;
        float ot[8];
        #pragma unroll
        for (int j = 0; j < 8; ++j) {
            float y = acc[c][j] + bb[j];
            ot[j] = y >= 0.f ? y : alpha * y;
        }
        float* op = out + (size_t)id * ODIM + og * 8;
        *(float4*)&op[0] = *(const float4*)&ot[0];
        *(float4*)&op[4] = *(const float4*)&ot[4];
    }
}

extern "C" void kernel_launch(void* const* d_in, const int* in_sizes, int n_in,
                              void* d_out, int out_size, void* d_ws, size_t ws_size,
                              hipStream_t stream) {
    const float* last    = (const float*)d_in[0];
    const float* W       = (const float*)d_in[1];
    const float* bias    = (const float*)d_in[2];
    const float* alpha   = (const float*)d_in[3];
    const int*   vec     = (const int*)d_in[4];
    const int*   dmap    = (const int*)d_in[5];
    const int*   drev    = (const int*)d_in[6];
    const int*   child_l = (const int*)d_in[7];
    const int*   child_r = (const int*)d_in[8];
    float* out = (float*)d_out;
    int*   ws  = (int*)d_ws;

    zero_kernel<<<1, 64, 0, stream>>>(ws);
    count_kernel<<<TOTAL / 256, 256, 0, stream>>>(vec, dmap, ws);
    prefix_kernel<<<1, 64, 0, stream>>>(ws);
    scatter_kernel<<<TOTAL / 256, 256, 0, stream>>>(vec, dmap, ws);
    dim3 grid(TOTAL / BM, NDIR);
    gemm_kernel<<<grid, 256, 0, stream>>>(last, W, bias, alpha, vec, drev,
                                          child_l, child_r, ws, out);
}